// Round 1
// baseline (366.481 us; speedup 1.0000x reference)
//
#include <hip/hip_runtime.h>

#define HH 1024
#define WW 1024
#define BH 32          // output rows per block -> 32 strips x 48 images = 1536 blocks
#define RAD 4
#define NSTRIP (HH / BH)   // 32, power of two

typedef float vfloat4 __attribute__((ext_vector_type(4)));

struct HS { float h0, h1, h2, h3; };

// horizontal 9-wide clipped sums for 4 consecutive columns, via 3 overlapping
// float4 loads (L1/L2 absorb the 3x request amplification; HBM fetch ~1x)
__device__ __forceinline__ HS hsum_row(const float* __restrict__ row, int c,
                                       bool first, bool last) {
    float4 b = *(const float4*)(row + c);
    float4 a, d;
    if (first) a = make_float4(0.f, 0.f, 0.f, 0.f);
    else       a = *(const float4*)(row + c - 4);
    if (last)  d = make_float4(0.f, 0.f, 0.f, 0.f);
    else       d = *(const float4*)(row + c + 4);
    HS h;
    h.h0 = ((a.x + a.y) + (a.z + a.w)) + ((b.x + b.y) + (b.z + b.w)) + d.x;
    h.h1 = h.h0 - a.x + d.y;
    h.h2 = h.h1 - a.y + d.z;
    h.h3 = h.h2 - a.z + d.w;
    return h;
}

// Fast path: interior strips, constant vertical count 9 folded into weights.
// J is a compile-time literal so ring[] stays in registers.
#define STEP_FAST(J) do {                                                  \
    HS h = hsum_row(rowp, c, first, last);                                 \
    vs0 += h.h0 - ring[J].h0;                                              \
    vs1 += h.h1 - ring[J].h1;                                              \
    vs2 += h.h2 - ring[J].h2;                                              \
    vs3 += h.h3 - ring[J].h3;                                              \
    ring[J] = h;                                                           \
    vfloat4 o4 = {vs0 * w0, vs1 * w1, vs2 * w2, vs3 * w3};                 \
    __builtin_nontemporal_store(o4, (vfloat4*)(op + c));                   \
    rowp += WW; op += WW;                                                  \
} while (0)

// Generic path: top/bottom strips (2 of 32), with row clipping + count.
#define STEP_GEN(J) do {                                                   \
    int rl = r + RAD;                                                      \
    HS h;                                                                  \
    if (rl < HH) h = hsum_row(xin + (size_t)rl * WW, c, first, last);      \
    else { h.h0 = 0.f; h.h1 = 0.f; h.h2 = 0.f; h.h3 = 0.f; }               \
    vs0 += h.h0 - ring[J].h0;                                              \
    vs1 += h.h1 - ring[J].h1;                                              \
    vs2 += h.h2 - ring[J].h2;                                              \
    vs3 += h.h3 - ring[J].h3;                                              \
    ring[J] = h;                                                           \
    int lo = r - RAD; if (lo < 0) lo = 0;                                  \
    int hi = r + RAD; if (hi > HH - 1) hi = HH - 1;                        \
    float ich = 1.0f / (float)(hi - lo + 1);                               \
    vfloat4 o4 = {vs0 * ich * sw[0], vs1 * ich * sw[1],                    \
                  vs2 * ich * sw[2], vs3 * ich * sw[3]};                   \
    __builtin_nontemporal_store(o4, (vfloat4*)(o + (size_t)r * WW + c));   \
    ++r;                                                                   \
} while (0)

__global__ __launch_bounds__(256, 4)
void box_kernel(const float* __restrict__ x, float* __restrict__ out) {
    const int tid = threadIdx.x;

    // XCD-aware bijective swizzle: HW round-robins consecutive blockIdx across
    // 8 XCDs; remap so each XCD owns a contiguous chunk (= whole images), so
    // adjacent strips share their 9-row halo in the same L2. 1536 % 8 == 0.
    const int lin  = blockIdx.x + NSTRIP * blockIdx.y;
    const int nblk = NSTRIP * gridDim.y;
    const int cpx  = nblk >> 3;
    const int swz  = (lin & 7) * cpx + (lin >> 3);
    const int strip = swz & (NSTRIP - 1);
    const int img   = swz / NSTRIP;

    const int r0 = strip * BH;
    const int c  = tid * 4;
    const bool first = (tid == 0);
    const bool last  = (tid == 255);

    const float* __restrict__ xin = x + (size_t)img * (HH * WW);
    float* __restrict__ o = out + (size_t)img * (HH * WW);

    // per-column horizontal counts (constant over rows)
    float sw[4];
#pragma unroll
    for (int j = 0; j < 4; ++j) {
        int cc = c + j;
        int lo = cc - RAD < 0 ? 0 : cc - RAD;
        int hi = cc + RAD > WW - 1 ? WW - 1 : cc + RAD;
        sw[j] = 1.0f / (float)(hi - lo + 1);
    }

    // ---- prime: rows r0-5 .. r0+3 into register ring slots 0..8 ----
    HS ring[9];
    float vs0 = 0.f, vs1 = 0.f, vs2 = 0.f, vs3 = 0.f;
#pragma unroll
    for (int k = 0; k < 9; ++k) {
        int rr = r0 - RAD - 1 + k;
        HS h;
        if (rr >= 0) h = hsum_row(xin + (size_t)rr * WW, c, first, last);
        else { h.h0 = 0.f; h.h1 = 0.f; h.h2 = 0.f; h.h3 = 0.f; }
        ring[k] = h;
        vs0 += h.h0; vs1 += h.h1; vs2 += h.h2; vs3 += h.h3;
    }

    // interior: no row clipping anywhere in the main loop
    const bool interior = (r0 >= RAD) && (r0 + BH + RAD <= HH);

    if (interior) {
        const float w0 = sw[0] * (1.0f / 9.0f);
        const float w1 = sw[1] * (1.0f / 9.0f);
        const float w2 = sw[2] * (1.0f / 9.0f);
        const float w3 = sw[3] * (1.0f / 9.0f);
        const float* __restrict__ rowp = xin + (size_t)(r0 + RAD) * WW;
        float* __restrict__ op = o + (size_t)r0 * WW;
        // 32 rows = 3 chunks of 9 (ring realigns each chunk) + 5 tail
#pragma unroll 1
        for (int chunk = 0; chunk < 3; ++chunk) {
            STEP_FAST(0); STEP_FAST(1); STEP_FAST(2); STEP_FAST(3); STEP_FAST(4);
            STEP_FAST(5); STEP_FAST(6); STEP_FAST(7); STEP_FAST(8);
        }
        STEP_FAST(0); STEP_FAST(1); STEP_FAST(2); STEP_FAST(3); STEP_FAST(4);
    } else {
        int r = r0;
#pragma unroll 1
        for (int chunk = 0; chunk < 3; ++chunk) {
            STEP_GEN(0); STEP_GEN(1); STEP_GEN(2); STEP_GEN(3); STEP_GEN(4);
            STEP_GEN(5); STEP_GEN(6); STEP_GEN(7); STEP_GEN(8);
        }
        STEP_GEN(0); STEP_GEN(1); STEP_GEN(2); STEP_GEN(3); STEP_GEN(4);
    }
}

extern "C" void kernel_launch(void* const* d_in, const int* in_sizes, int n_in,
                              void* d_out, int out_size, void* d_ws, size_t ws_size,
                              hipStream_t stream) {
    const float* x = (const float*)d_in[0];
    float* out = (float*)d_out;
    int n_images = in_sizes[0] / (HH * WW);   // 16*3 = 48
    dim3 grid(NSTRIP, n_images);              // 32 x 48 = 1536 blocks
    dim3 block(256);
    box_kernel<<<grid, block, 0, stream>>>(x, out);
}